// Round 7
// baseline (1869.710 us; speedup 1.0000x reference)
//
#include <hip/hip_runtime.h>
#include <hip/hip_bf16.h>
#include <math.h>

#define BB 32
#define SS 256
#define EE 512
#define HH 1024
#define LDM 256
#define NROW (BB*SS)   // 8192
#define NWG 64         // cooperative wgs for recurrence (1 per 4 CUs; all resident)

typedef __attribute__((ext_vector_type(8))) short bf16x8;
typedef __attribute__((ext_vector_type(4))) float f32x4;
typedef unsigned long long u64;

static __device__ inline unsigned short f2bf(float f){
  unsigned u = __float_as_uint(f);
  unsigned r = (u + 0x7fffu + ((u >> 16) & 1u)) >> 16;
  return (unsigned short)r;
}
// cheap round (no tie-to-even) for GEMM staging
static __device__ inline unsigned short f2bf_fast(float f){
  return (unsigned short)((__float_as_uint(f) + 0x8000u) >> 16);
}
static __device__ inline bf16x8 cvt8(float4 x, float4 y){
  union { ushort s[8]; bf16x8 v; } t;
  t.s[0]=f2bf_fast(x.x); t.s[1]=f2bf_fast(x.y); t.s[2]=f2bf_fast(x.z); t.s[3]=f2bf_fast(x.w);
  t.s[4]=f2bf_fast(y.x); t.s[5]=f2bf_fast(y.y); t.s[6]=f2bf_fast(y.z); t.s[7]=f2bf_fast(y.w);
  return t.v;
}
static __device__ inline unsigned packbf(float a, float b){
  return (unsigned)f2bf(a) | ((unsigned)f2bf(b) << 16);
}

// fast tanh: 1 - 2/(e^{2x}+1)
static __device__ inline float ftanh(float x){
  float e = __expf(2.f*x);
  return 1.f - 2.f/(e + 1.f);
}

// coherent (L1/L2-bypass, LLC-read) 16B load on the NORMAL coalescing path.
// Result lands asynchronously: caller must s_waitcnt vmcnt(0) + sched_barrier
// before first use.
#define GLD(dst, p) asm volatile("global_load_dwordx4 %0, %1, off sc0 sc1" \
                                 : "=v"(dst) : "v"(p) : "memory")

static __device__ inline bf16x8 asbf(f32x4 x){
  union { f32x4 f; bf16x8 b; } u; u.f = x; return u.b;
}

// ---------------- sort (stable argsort by descending length) ----------------
__global__ void k_sort(const int* __restrict__ length, int* __restrict__ sorted_idx){
  int b = threadIdx.x;
  if (b >= BB) return;
  int lb = length[b];
  int r = 0;
  for (int o = 0; o < BB; ++o){
    int lo = length[o];
    if (lo > lb || (lo == lb && o < b)) ++r;
  }
  sorted_idx[r] = b;
}

// token / target maps in sorted order
__global__ void k_maps(const int* __restrict__ sorted_idx,
                       const int* __restrict__ inp_seq, const int* __restrict__ tgt_seq,
                       int* __restrict__ tokmap, int* __restrict__ tgtmap){
  int bs = blockIdx.x; int t = threadIdx.x;
  int b = sorted_idx[bs];
  tokmap[bs*SS + t] = inp_seq[b*SS + t];
  tgtmap[bs*SS + t] = tgt_seq[b*SS + t];
}

// hid = z @ l2h_w.T + l2h_b, written DIRECTLY in bf16 fragment-major layout
__global__ __launch_bounds__(256) void k_hid(const float* __restrict__ z,
        const float* __restrict__ w, const float* __restrict__ bias,
        ushort* __restrict__ hb0){
  int id = blockIdx.x*256 + threadIdx.x;      // flat [B,2H] index = b*2048 + c
  int b = id >> 11, c = id & 2047;
  const float4* zr = (const float4*)(z + b*LDM);
  const float4* wr = (const float4*)(w + (size_t)c*LDM);
  float a0=0,a1=0,a2=0,a3=0;
  #pragma unroll 4
  for (int k=0;k<LDM/4;k++){ float4 zz=zr[k], ww=wr[k];
    a0+=zz.x*ww.x; a1+=zz.y*ww.y; a2+=zz.z*ww.z; a3+=zz.w*ww.w; }
  float val = a0+a1+a2+a3 + bias[c];
  int layer = id >> 15, bp = (id >> 10) & 31, j = id & 1023;
  hb0[(layer<<15) + ((j>>3)<<8) + (bp<<3) + (j&7)] = f2bf(val);
}

// concat [head_w(33); p0(256); p1(64); p2(16); zeros(15)] -> wcat[384][1024]
__global__ __launch_bounds__(256) void k_wcat(
    const float* __restrict__ head_w, const float* __restrict__ p0,
    const float* __restrict__ p1, const float* __restrict__ p2,
    float* __restrict__ wcat){
  int row = blockIdx.x; int t = threadIdx.x;
  float4* dst = (float4*)(wcat + (size_t)row*HH);
  const float* src;
  if      (row < 33)  src = head_w + (size_t)row*HH;
  else if (row < 289) src = p0 + (size_t)(row-33)*HH;
  else if (row < 353) src = p1 + (size_t)(row-289)*HH;
  else if (row < 369) src = p2 + (size_t)(row-353)*HH;
  else { dst[t] = make_float4(0.f,0.f,0.f,0.f); return; }
  dst[t] = ((const float4*)src)[t];
}

// ---------------- bf16 MFMA GEMM: C[M,N] = A[M,K] @ Bm[N,K]^T (+bias0+bias1)
__global__ __launch_bounds__(256) void k_gemm_bf16(
    const float* __restrict__ A, int lda, const int* __restrict__ rowmap,
    const float* __restrict__ Bm,
    const float* __restrict__ bias0, const float* __restrict__ bias1,
    float* __restrict__ C, int M, int N, int K)
{
  __shared__ ushort As[128*72];   // pad 64->72 elems: frag reads 2-way (free)
  __shared__ ushort Bs[128*72];
  const int nt = blockIdx.x * 128, mt = blockIdx.y * 128;
  const int tid = threadIdx.x;
  const int wv = tid >> 6, ln = tid & 63;
  const int wm = wv & 1, wn = wv >> 1;          // 2x2 wave grid (64x64 each)
  const int lc = ln & 15, quad = ln >> 4;
  f32x4 acc[4][4] = {{{0.f,0.f,0.f,0.f}}};

  for (int s = 0; s < K; s += 64){
    __syncthreads();
    #pragma unroll
    for (int cc = 0; cc < 4; ++cc){
      int ch = tid*4 + cc;                 // 0..1023: row=ch>>3, chunk=ch&7
      int r = ch >> 3, c = ch & 7;
      int ar = mt + r;
      const float* ap = A + (size_t)(rowmap ? rowmap[ar] : ar)*lda + s + c*8;
      float4 x = *(const float4*)ap, y = *(const float4*)(ap+4);
      *(bf16x8*)&As[r*72 + c*8] = cvt8(x, y);
      int br = nt + r; if (br >= N) br = N - 1;
      const float* bp = Bm + (size_t)br*K + s + c*8;
      float4 bx = *(const float4*)bp, by = *(const float4*)(bp+4);
      *(bf16x8*)&Bs[r*72 + c*8] = cvt8(bx, by);
    }
    __syncthreads();
    #pragma unroll
    for (int kq = 0; kq < 2; ++kq){
      int cq = kq*4 + quad;
      bf16x8 af[4], bfv[4];
      #pragma unroll
      for (int i=0;i<4;i++) af[i]  = *(const bf16x8*)&As[(wm*64 + i*16 + lc)*72 + cq*8];
      #pragma unroll
      for (int j=0;j<4;j++) bfv[j] = *(const bf16x8*)&Bs[(wn*64 + j*16 + lc)*72 + cq*8];
      #pragma unroll
      for (int i=0;i<4;i++)
        #pragma unroll
        for (int j=0;j<4;j++)
          acc[i][j] = __builtin_amdgcn_mfma_f32_16x16x32_bf16(af[i], bfv[j], acc[i][j], 0, 0, 0);
    }
  }
  #pragma unroll
  for (int j=0;j<4;j++){
    int col = nt + wn*64 + j*16 + lc;
    if (col < N){
      float badd = (bias0 ? bias0[col] : 0.f) + (bias1 ? bias1[col] : 0.f);
      #pragma unroll
      for (int i=0;i<4;i++){
        int row = mt + wm*64 + i*16 + quad*4;
        #pragma unroll
        for (int r=0;r<4;r++)
          C[(size_t)(row+r)*N + col] = acc[i][j][r] + badd;
      }
    }
  }
}

// ---------------- fused 2-layer pipelined persistent RNN recurrence ----------------
// R6 structure (proven, 1008us) with ONE change: wave-granular publish + poll.
//   - Each WAVE drains its own protocol stores (vmcnt is wave-level) and lane0
//     bumps this WG's 128B-strided counter line (64 lines, 4 bumps/line/round).
//     The pre-bump __syncthreads is GONE: the publish happens as soon as the
//     last-finishing wave drains, with no WG-barrier + single-bump serialization.
//   - Wave 0's 64 lanes poll the 64 lines (one line/lane) with two alternating
//     in-flight loads (sampling ~RTT/2 instead of a dependent-load chain), then
//     one __syncthreads releases the WG.
// Lap safety unchanged: poll passes only after all 256 wave-bumps of round r;
// each wave's bump follows the vmcnt(0) drain of ITS loads and stores of round
// r, so no parity buffer is overwritten while still being read. red[] reuse is
// protected by the post-poll __syncthreads (every wave's red reads precede its
// bump, which precedes the barrier).
__global__ __launch_bounds__(256, 1) void k_rnn_fused(
    const float* __restrict__ pre0, float* __restrict__ h2out,
    const float* __restrict__ w0hh, const float* __restrict__ w1ih,
    const float* __restrict__ w1hh,
    const float* __restrict__ b1ih, const float* __restrict__ b1hh,
    const ushort* __restrict__ hb0, ushort* __restrict__ hx, int* flags)
{
  __shared__ ushort w0F[16384], wiF[16384], whF[16384];  // frag-order weight slices
  __shared__ float red[4352];                            // [2 sets][wv][row 0..31][17]
  const int wg  = blockIdx.x;
  const int tid = threadIdx.x;
  const int j0  = wg * 16;
  int* ctr = flags + wg * 32;                 // per-WG 128B-strided counter line

  // stage the three 16x1024 weight slices as bf16 in MFMA fragment order
  for (int c = tid; c < 4096; c += 256){
    int rr = c >> 8, cc = (c & 255) * 4;
    int dst = ((cc >> 3)*16 + rr)*8 + (cc & 7);
    size_t srow = (size_t)(j0 + rr)*HH + cc;
    float4 w4; uint2 p;
    w4 = *(const float4*)&w0hh[srow];
    p.x = packbf(w4.x, w4.y); p.y = packbf(w4.z, w4.w);
    *(uint2*)&w0F[dst] = p;
    w4 = *(const float4*)&w1ih[srow];
    p.x = packbf(w4.x, w4.y); p.y = packbf(w4.z, w4.w);
    *(uint2*)&wiF[dst] = p;
    w4 = *(const float4*)&w1hh[srow];
    p.x = packbf(w4.x, w4.y); p.y = packbf(w4.z, w4.w);
    *(uint2*)&whF[dst] = p;
  }
  const int lane = tid & 63, wv = tid >> 6;
  const int col = lane & 15, quad = lane >> 4;
  const int ob = tid >> 3, oj = (tid << 1) & 15;

  float2 pre = *(const float2*)&pre0[((size_t)ob*SS + 0)*HH + j0 + oj];
  float2 pre2;
  pre2.x = b1ih[j0+oj]   + b1hh[j0+oj];
  pre2.y = b1ih[j0+oj+1] + b1hh[j0+oj+1];
  __syncthreads();

  for (int r = 0; r < SS; ++r){
    // h1[r-1] fragments (shared by both layer updates)
    const u64* s1 = (const u64*)(r == 0 ? hb0 : hx + ((r-1)&1)*32768);
    const u64* s2 = (r == 0) ? (const u64*)hb0
                  : (const u64*)(r == 1 ? hb0 + 32768 : hx + (2 + (r&1))*32768);
    f32x4 a0r[8], a1r[8], c0r[8], c1r[8];
    #pragma unroll
    for (int ks = 0; ks < 8; ++ks){
      int kb = wv*32 + ks*4 + quad;
      const u64* p = s1 + (kb << 6) + (col << 1);
      GLD(a0r[ks], p);
      GLD(a1r[ks], p + 32);
    }
    if (r > 0){
      #pragma unroll
      for (int ks = 0; ks < 8; ++ks){
        int kb = wv*32 + ks*4 + quad;
        const u64* p = s2 + (kb << 6) + (col << 1);
        GLD(c0r[ks], p);
        GLD(c1r[ks], p + 32);
      }
    }
    asm volatile("s_waitcnt vmcnt(0)" ::: "memory");
    __builtin_amdgcn_sched_barrier(0);

    f32x4 accA0 = {0.f,0.f,0.f,0.f}, accA1 = {0.f,0.f,0.f,0.f};
    f32x4 accB0 = {0.f,0.f,0.f,0.f}, accB1 = {0.f,0.f,0.f,0.f};
    #pragma unroll
    for (int ks = 0; ks < 8; ++ks){
      int kb = wv*32 + ks*4 + quad;
      bf16x8 b0 = *(const bf16x8*)&w0F[(kb*16 + col)*8];
      accA0 = __builtin_amdgcn_mfma_f32_16x16x32_bf16(asbf(a0r[ks]), b0, accA0, 0, 0, 0);
      accA1 = __builtin_amdgcn_mfma_f32_16x16x32_bf16(asbf(a1r[ks]), b0, accA1, 0, 0, 0);
      bf16x8 bi = *(const bf16x8*)&wiF[(kb*16 + col)*8];
      accB0 = __builtin_amdgcn_mfma_f32_16x16x32_bf16(asbf(a0r[ks]), bi, accB0, 0, 0, 0);
      accB1 = __builtin_amdgcn_mfma_f32_16x16x32_bf16(asbf(a1r[ks]), bi, accB1, 0, 0, 0);
    }
    if (r > 0){
      #pragma unroll
      for (int ks = 0; ks < 8; ++ks){
        int kb = wv*32 + ks*4 + quad;
        bf16x8 bh = *(const bf16x8*)&whF[(kb*16 + col)*8];
        accB0 = __builtin_amdgcn_mfma_f32_16x16x32_bf16(asbf(c0r[ks]), bh, accB0, 0, 0, 0);
        accB1 = __builtin_amdgcn_mfma_f32_16x16x32_bf16(asbf(c1r[ks]), bh, accB1, 0, 0, 0);
      }
    }
    #pragma unroll
    for (int q = 0; q < 4; ++q){
      red[wv*544 + (quad*4 + q)*17 + col]             = accA0[q];
      red[wv*544 + (16 + quad*4 + q)*17 + col]        = accA1[q];
      red[2176 + wv*544 + (quad*4 + q)*17 + col]      = accB0[q];
      red[2176 + wv*544 + (16 + quad*4 + q)*17 + col] = accB1[q];
    }
    __syncthreads();

    int ro = ob*17 + oj;
    float s0 = red[ro]   + red[544 + ro]   + red[1088 + ro]   + red[1632 + ro];
    float s1v= red[ro+1] + red[544 + ro+1] + red[1088 + ro+1] + red[1632 + ro+1];
    float v0 = ftanh(pre.x + s0);
    float v1 = ftanh(pre.y + s1v);
    int k = j0 + oj;
    unsigned off = ((unsigned)(k >> 3) << 7) + ((unsigned)ob << 2) + ((unsigned)(k & 7) >> 1);
    __hip_atomic_store((unsigned*)(hx + (r&1)*32768) + off, packbf(v0, v1),
                       __ATOMIC_RELAXED, __HIP_MEMORY_SCOPE_AGENT);
    float w0v = 0.f, w1v = 0.f;
    if (r > 0){
      float s2v = red[2176+ro]   + red[2720+ro]   + red[3264+ro]   + red[3808+ro];
      float s3v = red[2176+ro+1] + red[2720+ro+1] + red[3264+ro+1] + red[3808+ro+1];
      w0v = ftanh(pre2.x + s2v);
      w1v = ftanh(pre2.y + s3v);
      __hip_atomic_store((unsigned*)(hx + (2 + ((r-1)&1))*32768) + off, packbf(w0v, w1v),
                         __ATOMIC_RELAXED, __HIP_MEMORY_SCOPE_AGENT);
    }
    // wave-granular publish: THIS wave's stores drained -> lane0 bumps the
    // WG's counter line (4 bumps/line/round; 64 lines in parallel)
    asm volatile("s_waitcnt vmcnt(0)" ::: "memory");
    if (lane == 0)
      __hip_atomic_fetch_add(ctr, 1, __ATOMIC_RELAXED, __HIP_MEMORY_SCOPE_AGENT);

    // off-protocol (cached): fp32 h2 for later GEMMs + next pre0 prefetch
    if (r > 0)
      *(float2*)&h2out[((size_t)ob*SS + (r-1))*HH + j0 + oj] = make_float2(w0v, w1v);
    int tn = (r + 1 < SS) ? r + 1 : SS - 1;
    pre = *(const float2*)&pre0[((size_t)ob*SS + tn)*HH + j0 + oj];

    // wave 0 polls all 64 counter lines (one per lane), two loads in flight
    if (tid < 64){
      int tv = 4 * (r + 1);
      const int* fp = flags + tid*32;
      int va = __hip_atomic_load(fp, __ATOMIC_RELAXED, __HIP_MEMORY_SCOPE_AGENT);
      int vb = __hip_atomic_load(fp, __ATOMIC_RELAXED, __HIP_MEMORY_SCOPE_AGENT);
      while (!__all(va >= tv)){
        va = vb;
        vb = __hip_atomic_load(fp, __ATOMIC_RELAXED, __HIP_MEMORY_SCOPE_AGENT);
      }
    }
    __syncthreads();
  }

  // epilogue: h2[255] = tanh(b1 + h1[255] @ W1ih^T + h2[254] @ W1hh^T)
  {
    const u64* s1 = (const u64*)(hx + 32768);       // h1[255] (parity 1)
    const u64* s2 = (const u64*)(hx + 2*32768);     // h2[254] (parity 0)
    f32x4 a0r[8], a1r[8], c0r[8], c1r[8];
    #pragma unroll
    for (int ks = 0; ks < 8; ++ks){
      int kb = wv*32 + ks*4 + quad;
      const u64* p1 = s1 + (kb << 6) + (col << 1);
      GLD(a0r[ks], p1); GLD(a1r[ks], p1 + 32);
      const u64* p2 = s2 + (kb << 6) + (col << 1);
      GLD(c0r[ks], p2); GLD(c1r[ks], p2 + 32);
    }
    asm volatile("s_waitcnt vmcnt(0)" ::: "memory");
    __builtin_amdgcn_sched_barrier(0);
    f32x4 accB0 = {0.f,0.f,0.f,0.f}, accB1 = {0.f,0.f,0.f,0.f};
    #pragma unroll
    for (int ks = 0; ks < 8; ++ks){
      int kb = wv*32 + ks*4 + quad;
      bf16x8 bi = *(const bf16x8*)&wiF[(kb*16 + col)*8];
      accB0 = __builtin_amdgcn_mfma_f32_16x16x32_bf16(asbf(a0r[ks]), bi, accB0, 0, 0, 0);
      accB1 = __builtin_amdgcn_mfma_f32_16x16x32_bf16(asbf(a1r[ks]), bi, accB1, 0, 0, 0);
      bf16x8 bh = *(const bf16x8*)&whF[(kb*16 + col)*8];
      accB0 = __builtin_amdgcn_mfma_f32_16x16x32_bf16(asbf(c0r[ks]), bh, accB0, 0, 0, 0);
      accB1 = __builtin_amdgcn_mfma_f32_16x16x32_bf16(asbf(c1r[ks]), bh, accB1, 0, 0, 0);
    }
    #pragma unroll
    for (int q = 0; q < 4; ++q){
      red[wv*544 + (quad*4 + q)*17 + col]      = accB0[q];
      red[wv*544 + (16 + quad*4 + q)*17 + col] = accB1[q];
    }
    __syncthreads();
    int ro = ob*17 + oj;
    float s2v = red[ro]   + red[544 + ro]   + red[1088 + ro]   + red[1632 + ro];
    float s3v = red[ro+1] + red[544 + ro+1] + red[1088 + ro+1] + red[1632 + ro+1];
    *(float2*)&h2out[((size_t)ob*SS + (SS-1))*HH + j0 + oj] =
        make_float2(ftanh(pre2.x + s2v), ftanh(pre2.y + s3v));
  }
}

// ---------------- fused cluster logsumexp (proj strided into combo buffer) ----
__global__ __launch_bounds__(256) void k_cluster(
    const float* __restrict__ proj, int ld, int Kp,
    const float* __restrict__ W, int Nc,
    float* __restrict__ stats, int ci)
{
  __shared__ float ps[4][4][256];
  int lane = threadIdx.x & 63;
  int wvl  = threadIdx.x >> 6;
  int r0 = (blockIdx.x*4 + wvl) * 4;
  for (int r=0;r<4;r++)
    for (int k=lane;k<Kp;k+=64)
      ps[wvl][r][k] = proj[(size_t)(r0+r)*ld + k];
  __syncthreads();
  float mx[4], sm[4];
  #pragma unroll
  for (int r=0;r<4;r++){ mx[r]=-1e30f; sm[r]=0.f; }
  for (int n=lane; n<Nc; n+=64){
    const float* wr = W + (size_t)n*Kp;
    float l[4]={0.f,0.f,0.f,0.f};
    for (int k=0;k<Kp;k+=4){
      float4 w4 = *(const float4*)(wr+k);
      #pragma unroll
      for (int r=0;r<4;r++){
        l[r] += w4.x*ps[wvl][r][k] + w4.y*ps[wvl][r][k+1]
              + w4.z*ps[wvl][r][k+2] + w4.w*ps[wvl][r][k+3];
      }
    }
    #pragma unroll
    for (int r=0;r<4;r++){
      float nm = fmaxf(mx[r], l[r]);
      sm[r] = sm[r]*__expf(mx[r]-nm) + __expf(l[r]-nm);
      mx[r] = nm;
    }
  }
  #pragma unroll
  for (int r=0;r<4;r++){
    for (int off=32; off; off>>=1){
      float om = __shfl_down(mx[r], off);
      float os = __shfl_down(sm[r], off);
      float nm = fmaxf(mx[r], om);
      sm[r] = sm[r]*__expf(mx[r]-nm) + os*__expf(om-nm);
      mx[r] = nm;
    }
    if (lane==0){
      stats[(size_t)(r0+r)*6 + ci*2 + 0] = mx[r];
      stats[(size_t)(r0+r)*6 + ci*2 + 1] = sm[r];
    }
  }
}

// ---------------- target logit for tail clusters (one wave per row) ----------------
__global__ __launch_bounds__(256) void k_tlogit(
    const int* __restrict__ tgtmap, const float* __restrict__ combo,
    const float* __restrict__ w0, const float* __restrict__ w1, const float* __restrict__ w2,
    float* __restrict__ tlogit)
{
  int lane = threadIdx.x & 63;
  int row = (blockIdx.x * 256 + threadIdx.x) >> 6;
  int tgt = tgtmap[row];
  float acc = 0.f;
  const float* pr = nullptr; const float* wr = nullptr; int Kp = 0;
  const float* crow = combo + (size_t)row*384;
  if      (tgt >= 1000){ pr = crow + 353; wr = w2 + (size_t)(tgt-1000)*16;  Kp=16;  }
  else if (tgt >= 100) { pr = crow + 289; wr = w1 + (size_t)(tgt-100)*64;   Kp=64;  }
  else if (tgt >= 30)  { pr = crow + 33;  wr = w0 + (size_t)(tgt-30)*256;   Kp=256; }
  for (int k=lane; k<Kp; k+=64) acc += pr[k]*wr[k];
  for (int off=32; off; off>>=1) acc += __shfl_down(acc, off);
  if (lane==0) tlogit[row] = acc;
}

// ---------------- final: head LSE + assemble NLL, reduce ----------------
__global__ __launch_bounds__(256) void k_final(
    const float* __restrict__ combo, const float* __restrict__ stats,
    const float* __restrict__ tlogit, const int* __restrict__ tgtmap,
    float* __restrict__ out)
{
  int row = blockIdx.x*256 + threadIdx.x;
  int tgt = tgtmap[row];
  float nll = 0.f;
  if (tgt != 0){
    const float* hrow = combo + (size_t)row*384;
    float m = hrow[0];
    #pragma unroll
    for (int i=1;i<33;i++) m = fmaxf(m, hrow[i]);
    float s = 0.f;
    #pragma unroll
    for (int i=0;i<33;i++) s += __expf(hrow[i]-m);
    float lse = __logf(s) + m;
    int ci = (tgt>=1000) ? 2 : (tgt>=100) ? 1 : (tgt>=30) ? 0 : -1;
    if (ci < 0){
      nll = lse - hrow[tgt];
    } else {
      float cm = stats[(size_t)row*6 + ci*2 + 0];
      float cs = stats[(size_t)row*6 + ci*2 + 1];
      nll = lse - hrow[30+ci] + (__logf(cs) + cm - tlogit[row]);
    }
  }
  float v = nll;
  for (int off=32; off; off>>=1) v += __shfl_down(v, off);
  __shared__ float wsum[4];
  int lane = threadIdx.x & 63, wv = threadIdx.x >> 6;
  if (lane==0) wsum[wv] = v;
  __syncthreads();
  if (threadIdx.x==0) atomicAdd(out, wsum[0]+wsum[1]+wsum[2]+wsum[3]);
}

extern "C" void kernel_launch(void* const* d_in, const int* in_sizes, int n_in,
                              void* d_out, int out_size, void* d_ws, size_t ws_size,
                              hipStream_t stream)
{
  const float* z      = (const float*)d_in[0];
  const float* emb    = (const float*)d_in[1];
  const float* l2h_w  = (const float*)d_in[2];
  const float* l2h_b  = (const float*)d_in[3];
  const float* w0ih   = (const float*)d_in[4];
  const float* w0hh   = (const float*)d_in[5];
  const float* b0ih   = (const float*)d_in[6];
  const float* b0hh   = (const float*)d_in[7];
  const float* w1ih   = (const float*)d_in[8];
  const float* w1hh   = (const float*)d_in[9];
  const float* b1ih   = (const float*)d_in[10];
  const float* b1hh   = (const float*)d_in[11];
  const float* head_w = (const float*)d_in[12];
  const float* p0     = (const float*)d_in[13];
  const float* tw0    = (const float*)d_in[14];
  const float* p1     = (const float*)d_in[15];
  const float* tw1    = (const float*)d_in[16];
  const float* p2     = (const float*)d_in[17];
  const float* tw2    = (const float*)d_in[18];
  const int* inp_seq  = (const int*)d_in[19];
  const int* tgt_seq  = (const int*)d_in[20];
  const int* length   = (const int*)d_in[21];

  float* ws   = (float*)d_ws;
  ushort* hb0 = (ushort*)ws;                      // 65536 ushorts (2 layers initial)
  ushort* hx  = hb0 + 65536;                      // 131072 ushorts: h1 ping/pong, h2 ping/pong
  float* bufA = ws + 98304;                       // 8192*1024  (pre0; later combo etc.)
  float* bufB = bufA + (size_t)NROW*HH;           // 8192*1024  (h2)
  int*   ibuf = (int*)(bufB + (size_t)NROW*HH);
  int* sorted_idx = ibuf;                         // 32
  int* tokmap = ibuf + 32;                        // 8192
  int* tgtmap = tokmap + NROW;                    // 8192
  int* flags  = tgtmap + NROW;                    // 2048 ints: 64 per-WG lines @128B
  float* combo = bufA;                            // 8192*384 (head 0..32 | p0 33..288 | p1 289..352 | p2 353..368)
  float* stats = bufA + (size_t)NROW*384;         // 8192*6
  float* tlog  = stats + (size_t)NROW*6;          // 8192
  float* wcat  = tlog + NROW;                     // 384*1024

  float* outF = (float*)d_out;
  hipMemsetAsync(outF, 0, sizeof(float), stream);
  hipMemsetAsync(flags, 0, 2048*sizeof(int), stream);

  k_sort<<<1, 32, 0, stream>>>(length, sorted_idx);
  k_maps<<<32, 256, 0, stream>>>(sorted_idx, inp_seq, tgt_seq, tokmap, tgtmap);
  k_hid<<<256, 256, 0, stream>>>(z, l2h_w, l2h_b, hb0);

  // pre0 = emb[tok] @ w0ih^T + b0ih + b0hh   (bf16 MFMA, A gathered)
  k_gemm_bf16<<<dim3(HH/128, NROW/128), 256, 0, stream>>>(emb, EE, tokmap, w0ih,
                                                          b0ih, b0hh, bufA, NROW, HH, EE);
  // fused 2-layer pipelined recurrence: bufB := h2 (W1ih applied in-kernel)
  k_rnn_fused<<<NWG, 256, 0, stream>>>(bufA, bufB, w0hh, w1ih, w1hh, b1ih, b1hh,
                                       hb0, hx, flags);

  // single fused output GEMM: combo = h2 @ [head;p0;p1;p2]^T  (N=384, A read once)
  k_wcat<<<384, 256, 0, stream>>>(head_w, p0, p1, p2, wcat);
  k_gemm_bf16<<<dim3(3, NROW/128), 256, 0, stream>>>(bufB, HH, nullptr, wcat,
                                                     nullptr, nullptr, combo, NROW, 384, HH);

  k_cluster<<<NROW/16, 256, 0, stream>>>(combo + 33,  384, 256, tw0, 70,    stats, 0);
  k_cluster<<<NROW/16, 256, 0, stream>>>(combo + 289, 384, 64,  tw1, 900,   stats, 1);
  k_cluster<<<NROW/16, 256, 0, stream>>>(combo + 353, 384, 16,  tw2, 19000, stats, 2);
  k_tlogit<<<NROW/4, 256, 0, stream>>>(tgtmap, combo, tw0, tw1, tw2, tlog);
  k_final<<<NROW/256, 256, 0, stream>>>(combo, stats, tlog, tgtmap, outF);
}

// Round 8
// 1563.718 us; speedup vs baseline: 1.1957x; 1.1957x over previous
//
#include <hip/hip_runtime.h>
#include <hip/hip_bf16.h>
#include <math.h>

#define BB 32
#define SS 256
#define EE 512
#define HH 1024
#define LDM 256
#define NROW (BB*SS)   // 8192
#define NWG 64         // cooperative wgs for recurrence (1 per 4 CUs; all resident)

typedef __attribute__((ext_vector_type(8))) short bf16x8;
typedef __attribute__((ext_vector_type(4))) float f32x4;
typedef unsigned long long u64;

static __device__ inline unsigned short f2bf(float f){
  unsigned u = __float_as_uint(f);
  unsigned r = (u + 0x7fffu + ((u >> 16) & 1u)) >> 16;
  return (unsigned short)r;
}
// cheap round (no tie-to-even) for GEMM staging
static __device__ inline unsigned short f2bf_fast(float f){
  return (unsigned short)((__float_as_uint(f) + 0x8000u) >> 16);
}
static __device__ inline bf16x8 cvt8(float4 x, float4 y){
  union { ushort s[8]; bf16x8 v; } t;
  t.s[0]=f2bf_fast(x.x); t.s[1]=f2bf_fast(x.y); t.s[2]=f2bf_fast(x.z); t.s[3]=f2bf_fast(x.w);
  t.s[4]=f2bf_fast(y.x); t.s[5]=f2bf_fast(y.y); t.s[6]=f2bf_fast(y.z); t.s[7]=f2bf_fast(y.w);
  return t.v;
}
static __device__ inline unsigned packbf(float a, float b){
  return (unsigned)f2bf(a) | ((unsigned)f2bf(b) << 16);
}

// fast tanh: 1 - 2/(e^{2x}+1)
static __device__ inline float ftanh(float x){
  float e = __expf(2.f*x);
  return 1.f - 2.f/(e + 1.f);
}

// coherent (L1/L2-bypass, LLC-read) 16B load on the NORMAL coalescing path.
// Result lands asynchronously: caller must s_waitcnt vmcnt(0) + sched_barrier
// before first use.
#define GLD(dst, p) asm volatile("global_load_dwordx4 %0, %1, off sc0 sc1" \
                                 : "=v"(dst) : "v"(p) : "memory")

static __device__ inline bf16x8 asbf(f32x4 x){
  union { f32x4 f; bf16x8 b; } u; u.f = x; return u.b;
}

// ---------------- sort (stable argsort by descending length) ----------------
__global__ void k_sort(const int* __restrict__ length, int* __restrict__ sorted_idx){
  int b = threadIdx.x;
  if (b >= BB) return;
  int lb = length[b];
  int r = 0;
  for (int o = 0; o < BB; ++o){
    int lo = length[o];
    if (lo > lb || (lo == lb && o < b)) ++r;
  }
  sorted_idx[r] = b;
}

// token / target maps in sorted order
__global__ void k_maps(const int* __restrict__ sorted_idx,
                       const int* __restrict__ inp_seq, const int* __restrict__ tgt_seq,
                       int* __restrict__ tokmap, int* __restrict__ tgtmap){
  int bs = blockIdx.x; int t = threadIdx.x;
  int b = sorted_idx[bs];
  tokmap[bs*SS + t] = inp_seq[b*SS + t];
  tgtmap[bs*SS + t] = tgt_seq[b*SS + t];
}

// hid = z @ l2h_w.T + l2h_b, written DIRECTLY in bf16 fragment-major layout
__global__ __launch_bounds__(256) void k_hid(const float* __restrict__ z,
        const float* __restrict__ w, const float* __restrict__ bias,
        ushort* __restrict__ hb0){
  int id = blockIdx.x*256 + threadIdx.x;      // flat [B,2H] index = b*2048 + c
  int b = id >> 11, c = id & 2047;
  const float4* zr = (const float4*)(z + b*LDM);
  const float4* wr = (const float4*)(w + (size_t)c*LDM);
  float a0=0,a1=0,a2=0,a3=0;
  #pragma unroll 4
  for (int k=0;k<LDM/4;k++){ float4 zz=zr[k], ww=wr[k];
    a0+=zz.x*ww.x; a1+=zz.y*ww.y; a2+=zz.z*ww.z; a3+=zz.w*ww.w; }
  float val = a0+a1+a2+a3 + bias[c];
  int layer = id >> 15, bp = (id >> 10) & 31, j = id & 1023;
  hb0[(layer<<15) + ((j>>3)<<8) + (bp<<3) + (j&7)] = f2bf(val);
}

// concat [head_w(33); p0(256); p1(64); p2(16); zeros(15)] -> wcat[384][1024]
__global__ __launch_bounds__(256) void k_wcat(
    const float* __restrict__ head_w, const float* __restrict__ p0,
    const float* __restrict__ p1, const float* __restrict__ p2,
    float* __restrict__ wcat){
  int row = blockIdx.x; int t = threadIdx.x;
  float4* dst = (float4*)(wcat + (size_t)row*HH);
  const float* src;
  if      (row < 33)  src = head_w + (size_t)row*HH;
  else if (row < 289) src = p0 + (size_t)(row-33)*HH;
  else if (row < 353) src = p1 + (size_t)(row-289)*HH;
  else if (row < 369) src = p2 + (size_t)(row-353)*HH;
  else { dst[t] = make_float4(0.f,0.f,0.f,0.f); return; }
  dst[t] = ((const float4*)src)[t];
}

// bucket unmasked rows by target cluster (ballot-aggregated atomics)
__global__ __launch_bounds__(256) void k_bin(
    const int* __restrict__ tgtmap, int* __restrict__ cnt,
    int* __restrict__ l0, int* __restrict__ l1, int* __restrict__ l2)
{
  int row = blockIdx.x*256 + threadIdx.x;
  int tgt = tgtmap[row];
  int ci = (tgt == 0) ? -1 : (tgt >= 1000) ? 2 : (tgt >= 100) ? 1 : (tgt >= 30) ? 0 : -1;
  int lane = threadIdx.x & 63;
  #pragma unroll
  for (int c = 0; c < 3; ++c){
    unsigned long long mask = __ballot(ci == c);
    int nc = __popcll(mask);
    int base = 0;
    if (lane == 0 && nc) base = atomicAdd(&cnt[c], nc);
    base = __shfl(base, 0);
    if (ci == c){
      int pos = __popcll(mask & ((1ull << lane) - 1ull));
      int* lst = (c == 0) ? l0 : (c == 1) ? l1 : l2;
      lst[base + pos] = row;
    }
  }
}

// ---------------- bf16 MFMA GEMM: C[M,N] = A[M,K] @ Bm[N,K]^T (+bias0+bias1)
__global__ __launch_bounds__(256) void k_gemm_bf16(
    const float* __restrict__ A, int lda, const int* __restrict__ rowmap,
    const float* __restrict__ Bm,
    const float* __restrict__ bias0, const float* __restrict__ bias1,
    float* __restrict__ C, int M, int N, int K)
{
  __shared__ ushort As[128*72];   // pad 64->72 elems: frag reads 2-way (free)
  __shared__ ushort Bs[128*72];
  const int nt = blockIdx.x * 128, mt = blockIdx.y * 128;
  const int tid = threadIdx.x;
  const int wv = tid >> 6, ln = tid & 63;
  const int wm = wv & 1, wn = wv >> 1;          // 2x2 wave grid (64x64 each)
  const int lc = ln & 15, quad = ln >> 4;
  f32x4 acc[4][4] = {{{0.f,0.f,0.f,0.f}}};

  for (int s = 0; s < K; s += 64){
    __syncthreads();
    #pragma unroll
    for (int cc = 0; cc < 4; ++cc){
      int ch = tid*4 + cc;                 // 0..1023: row=ch>>3, chunk=ch&7
      int r = ch >> 3, c = ch & 7;
      int ar = mt + r;
      const float* ap = A + (size_t)(rowmap ? rowmap[ar] : ar)*lda + s + c*8;
      float4 x = *(const float4*)ap, y = *(const float4*)(ap+4);
      *(bf16x8*)&As[r*72 + c*8] = cvt8(x, y);
      int br = nt + r; if (br >= N) br = N - 1;
      const float* bp = Bm + (size_t)br*K + s + c*8;
      float4 bx = *(const float4*)bp, by = *(const float4*)(bp+4);
      *(bf16x8*)&Bs[r*72 + c*8] = cvt8(bx, by);
    }
    __syncthreads();
    #pragma unroll
    for (int kq = 0; kq < 2; ++kq){
      int cq = kq*4 + quad;
      bf16x8 af[4], bfv[4];
      #pragma unroll
      for (int i=0;i<4;i++) af[i]  = *(const bf16x8*)&As[(wm*64 + i*16 + lc)*72 + cq*8];
      #pragma unroll
      for (int j=0;j<4;j++) bfv[j] = *(const bf16x8*)&Bs[(wn*64 + j*16 + lc)*72 + cq*8];
      #pragma unroll
      for (int i=0;i<4;i++)
        #pragma unroll
        for (int j=0;j<4;j++)
          acc[i][j] = __builtin_amdgcn_mfma_f32_16x16x32_bf16(af[i], bfv[j], acc[i][j], 0, 0, 0);
    }
  }
  #pragma unroll
  for (int j=0;j<4;j++){
    int col = nt + wn*64 + j*16 + lc;
    if (col < N){
      float badd = (bias0 ? bias0[col] : 0.f) + (bias1 ? bias1[col] : 0.f);
      #pragma unroll
      for (int i=0;i<4;i++){
        int row = mt + wm*64 + i*16 + quad*4;
        #pragma unroll
        for (int r=0;r<4;r++)
          C[(size_t)(row+r)*N + col] = acc[i][j][r] + badd;
      }
    }
  }
}

// ---------------- fused 2-layer pipelined persistent RNN recurrence ----------------
// EXACT R6 protocol (proven, 1008us): single phase per round, coalesced sc0/sc1
// loads, ONE vmcnt(0)+sched_barrier before all MFMAs, weights from LDS, two h
// stores, WG-granular drain+sync, tid0 bump to this WG's 128B-strided
// sub-counter (8 lines, 8-deep parallel RMW), tid<8 poll, sync.
// (R7's wave-granular publish + 64-lane poll REGRESSED +30%: poller-count x
// bump-count is the governing product; R6 minimizes it.)
__global__ __launch_bounds__(256, 1) void k_rnn_fused(
    const float* __restrict__ pre0, float* __restrict__ h2out,
    const float* __restrict__ w0hh, const float* __restrict__ w1ih,
    const float* __restrict__ w1hh,
    const float* __restrict__ b1ih, const float* __restrict__ b1hh,
    const ushort* __restrict__ hb0, ushort* __restrict__ hx, int* flags)
{
  __shared__ ushort w0F[16384], wiF[16384], whF[16384];  // frag-order weight slices
  __shared__ float red[4352];                            // [2 sets][wv][row 0..31][17]
  const int wg  = blockIdx.x;
  const int tid = threadIdx.x;
  const int j0  = wg * 16;
  int* ctr = flags + (wg & 7) * 32;           // 128B-strided sub-counter

  // stage the three 16x1024 weight slices as bf16 in MFMA fragment order
  for (int c = tid; c < 4096; c += 256){
    int rr = c >> 8, cc = (c & 255) * 4;
    int dst = ((cc >> 3)*16 + rr)*8 + (cc & 7);
    size_t srow = (size_t)(j0 + rr)*HH + cc;
    float4 w4; uint2 p;
    w4 = *(const float4*)&w0hh[srow];
    p.x = packbf(w4.x, w4.y); p.y = packbf(w4.z, w4.w);
    *(uint2*)&w0F[dst] = p;
    w4 = *(const float4*)&w1ih[srow];
    p.x = packbf(w4.x, w4.y); p.y = packbf(w4.z, w4.w);
    *(uint2*)&wiF[dst] = p;
    w4 = *(const float4*)&w1hh[srow];
    p.x = packbf(w4.x, w4.y); p.y = packbf(w4.z, w4.w);
    *(uint2*)&whF[dst] = p;
  }
  const int lane = tid & 63, wv = tid >> 6;
  const int col = lane & 15, quad = lane >> 4;
  const int ob = tid >> 3, oj = (tid << 1) & 15;

  float2 pre = *(const float2*)&pre0[((size_t)ob*SS + 0)*HH + j0 + oj];
  float2 pre2;
  pre2.x = b1ih[j0+oj]   + b1hh[j0+oj];
  pre2.y = b1ih[j0+oj+1] + b1hh[j0+oj+1];
  __syncthreads();

  for (int r = 0; r < SS; ++r){
    // h1[r-1] fragments (shared by both layer updates)
    const u64* s1 = (const u64*)(r == 0 ? hb0 : hx + ((r-1)&1)*32768);
    const u64* s2 = (r == 0) ? (const u64*)hb0
                  : (const u64*)(r == 1 ? hb0 + 32768 : hx + (2 + (r&1))*32768);
    f32x4 a0r[8], a1r[8], c0r[8], c1r[8];
    #pragma unroll
    for (int ks = 0; ks < 8; ++ks){
      int kb = wv*32 + ks*4 + quad;
      const u64* p = s1 + (kb << 6) + (col << 1);
      GLD(a0r[ks], p);
      GLD(a1r[ks], p + 32);
    }
    if (r > 0){
      #pragma unroll
      for (int ks = 0; ks < 8; ++ks){
        int kb = wv*32 + ks*4 + quad;
        const u64* p = s2 + (kb << 6) + (col << 1);
        GLD(c0r[ks], p);
        GLD(c1r[ks], p + 32);
      }
    }
    asm volatile("s_waitcnt vmcnt(0)" ::: "memory");
    __builtin_amdgcn_sched_barrier(0);

    f32x4 accA0 = {0.f,0.f,0.f,0.f}, accA1 = {0.f,0.f,0.f,0.f};
    f32x4 accB0 = {0.f,0.f,0.f,0.f}, accB1 = {0.f,0.f,0.f,0.f};
    #pragma unroll
    for (int ks = 0; ks < 8; ++ks){
      int kb = wv*32 + ks*4 + quad;
      bf16x8 b0 = *(const bf16x8*)&w0F[(kb*16 + col)*8];
      accA0 = __builtin_amdgcn_mfma_f32_16x16x32_bf16(asbf(a0r[ks]), b0, accA0, 0, 0, 0);
      accA1 = __builtin_amdgcn_mfma_f32_16x16x32_bf16(asbf(a1r[ks]), b0, accA1, 0, 0, 0);
      bf16x8 bi = *(const bf16x8*)&wiF[(kb*16 + col)*8];
      accB0 = __builtin_amdgcn_mfma_f32_16x16x32_bf16(asbf(a0r[ks]), bi, accB0, 0, 0, 0);
      accB1 = __builtin_amdgcn_mfma_f32_16x16x32_bf16(asbf(a1r[ks]), bi, accB1, 0, 0, 0);
    }
    if (r > 0){
      #pragma unroll
      for (int ks = 0; ks < 8; ++ks){
        int kb = wv*32 + ks*4 + quad;
        bf16x8 bh = *(const bf16x8*)&whF[(kb*16 + col)*8];
        accB0 = __builtin_amdgcn_mfma_f32_16x16x32_bf16(asbf(c0r[ks]), bh, accB0, 0, 0, 0);
        accB1 = __builtin_amdgcn_mfma_f32_16x16x32_bf16(asbf(c1r[ks]), bh, accB1, 0, 0, 0);
      }
    }
    #pragma unroll
    for (int q = 0; q < 4; ++q){
      red[wv*544 + (quad*4 + q)*17 + col]             = accA0[q];
      red[wv*544 + (16 + quad*4 + q)*17 + col]        = accA1[q];
      red[2176 + wv*544 + (quad*4 + q)*17 + col]      = accB0[q];
      red[2176 + wv*544 + (16 + quad*4 + q)*17 + col] = accB1[q];
    }
    __syncthreads();

    int ro = ob*17 + oj;
    float s0 = red[ro]   + red[544 + ro]   + red[1088 + ro]   + red[1632 + ro];
    float s1v= red[ro+1] + red[544 + ro+1] + red[1088 + ro+1] + red[1632 + ro+1];
    float v0 = ftanh(pre.x + s0);
    float v1 = ftanh(pre.y + s1v);
    int k = j0 + oj;
    unsigned off = ((unsigned)(k >> 3) << 7) + ((unsigned)ob << 2) + ((unsigned)(k & 7) >> 1);
    __hip_atomic_store((unsigned*)(hx + (r&1)*32768) + off, packbf(v0, v1),
                       __ATOMIC_RELAXED, __HIP_MEMORY_SCOPE_AGENT);
    float w0v = 0.f, w1v = 0.f;
    if (r > 0){
      float s2v = red[2176+ro]   + red[2720+ro]   + red[3264+ro]   + red[3808+ro];
      float s3v = red[2176+ro+1] + red[2720+ro+1] + red[3264+ro+1] + red[3808+ro+1];
      w0v = ftanh(pre2.x + s2v);
      w1v = ftanh(pre2.y + s3v);
      __hip_atomic_store((unsigned*)(hx + (2 + ((r-1)&1))*32768) + off, packbf(w0v, w1v),
                         __ATOMIC_RELAXED, __HIP_MEMORY_SCOPE_AGENT);
    }
    // all 256 threads' protocol stores durable at LLC, then ONE bump per wg
    asm volatile("s_waitcnt vmcnt(0)" ::: "memory");
    __syncthreads();
    if (tid == 0)
      __hip_atomic_fetch_add(ctr, 1, __ATOMIC_RELAXED, __HIP_MEMORY_SCOPE_AGENT);

    // off-protocol (cached): fp32 h2 for later GEMMs + next pre0 prefetch
    if (r > 0)
      *(float2*)&h2out[((size_t)ob*SS + (r-1))*HH + j0 + oj] = make_float2(w0v, w1v);
    int tn = (r + 1 < SS) ? r + 1 : SS - 1;
    pre = *(const float2*)&pre0[((size_t)ob*SS + tn)*HH + j0 + oj];

    // lanes 0..7 poll the 8 sub-counter lines with ONE load instruction/iter
    if (tid < 8){
      int tv = 8 * (r + 1);
      while (__hip_atomic_load(flags + tid*32, __ATOMIC_RELAXED,
                               __HIP_MEMORY_SCOPE_AGENT) < tv) {}
    }
    __syncthreads();
  }

  // epilogue: h2[255] = tanh(b1 + h1[255] @ W1ih^T + h2[254] @ W1hh^T)
  {
    const u64* s1 = (const u64*)(hx + 32768);       // h1[255] (parity 1)
    const u64* s2 = (const u64*)(hx + 2*32768);     // h2[254] (parity 0)
    f32x4 a0r[8], a1r[8], c0r[8], c1r[8];
    #pragma unroll
    for (int ks = 0; ks < 8; ++ks){
      int kb = wv*32 + ks*4 + quad;
      const u64* p1 = s1 + (kb << 6) + (col << 1);
      GLD(a0r[ks], p1); GLD(a1r[ks], p1 + 32);
      const u64* p2 = s2 + (kb << 6) + (col << 1);
      GLD(c0r[ks], p2); GLD(c1r[ks], p2 + 32);
    }
    asm volatile("s_waitcnt vmcnt(0)" ::: "memory");
    __builtin_amdgcn_sched_barrier(0);
    f32x4 accB0 = {0.f,0.f,0.f,0.f}, accB1 = {0.f,0.f,0.f,0.f};
    #pragma unroll
    for (int ks = 0; ks < 8; ++ks){
      int kb = wv*32 + ks*4 + quad;
      bf16x8 bi = *(const bf16x8*)&wiF[(kb*16 + col)*8];
      accB0 = __builtin_amdgcn_mfma_f32_16x16x32_bf16(asbf(a0r[ks]), bi, accB0, 0, 0, 0);
      accB1 = __builtin_amdgcn_mfma_f32_16x16x32_bf16(asbf(a1r[ks]), bi, accB1, 0, 0, 0);
      bf16x8 bh = *(const bf16x8*)&whF[(kb*16 + col)*8];
      accB0 = __builtin_amdgcn_mfma_f32_16x16x32_bf16(asbf(c0r[ks]), bh, accB0, 0, 0, 0);
      accB1 = __builtin_amdgcn_mfma_f32_16x16x32_bf16(asbf(c1r[ks]), bh, accB1, 0, 0, 0);
    }
    #pragma unroll
    for (int q = 0; q < 4; ++q){
      red[wv*544 + (quad*4 + q)*17 + col]      = accB0[q];
      red[wv*544 + (16 + quad*4 + q)*17 + col] = accB1[q];
    }
    __syncthreads();
    int ro = ob*17 + oj;
    float s2v = red[ro]   + red[544 + ro]   + red[1088 + ro]   + red[1632 + ro];
    float s3v = red[ro+1] + red[544 + ro+1] + red[1088 + ro+1] + red[1632 + ro+1];
    *(float2*)&h2out[((size_t)ob*SS + (SS-1))*HH + j0 + oj] =
        make_float2(ftanh(pre2.x + s2v), ftanh(pre2.y + s3v));
  }
}

// ---------------- cluster logsumexp over the BINNED row list only ----------------
__global__ __launch_bounds__(256) void k_cluster(
    const float* __restrict__ combo, int off, int ld, int Kp,
    const float* __restrict__ W, int Nc,
    const int* __restrict__ rowlist, const int* __restrict__ cntp, int ci,
    float* __restrict__ stats)
{
  __shared__ float ps[4][4][256];
  int lane = threadIdx.x & 63;
  int wvl  = threadIdx.x >> 6;
  int n0 = (blockIdx.x*4 + wvl) * 4;
  int count = cntp[ci];
  int rows[4];
  #pragma unroll
  for (int r=0;r<4;r++){
    rows[r] = (n0 + r < count) ? rowlist[n0 + r] : -1;
    if (rows[r] >= 0)
      for (int k=lane;k<Kp;k+=64)
        ps[wvl][r][k] = combo[(size_t)rows[r]*ld + off + k];
  }
  __syncthreads();
  if (rows[0] < 0) return;          // wave-uniform; list is compact so all 4 invalid

  float mx[4], sm[4];
  #pragma unroll
  for (int r=0;r<4;r++){ mx[r]=-1e30f; sm[r]=0.f; }
  for (int n=lane; n<Nc; n+=64){
    const float* wr = W + (size_t)n*Kp;
    float l[4]={0.f,0.f,0.f,0.f};
    for (int k=0;k<Kp;k+=4){
      float4 w4 = *(const float4*)(wr+k);
      #pragma unroll
      for (int r=0;r<4;r++){
        l[r] += w4.x*ps[wvl][r][k] + w4.y*ps[wvl][r][k+1]
              + w4.z*ps[wvl][r][k+2] + w4.w*ps[wvl][r][k+3];
      }
    }
    #pragma unroll
    for (int r=0;r<4;r++){
      float nm = fmaxf(mx[r], l[r]);
      sm[r] = sm[r]*__expf(mx[r]-nm) + __expf(l[r]-nm);
      mx[r] = nm;
    }
  }
  #pragma unroll
  for (int r=0;r<4;r++){
    for (int off2=32; off2; off2>>=1){
      float om = __shfl_down(mx[r], off2);
      float os = __shfl_down(sm[r], off2);
      float nm = fmaxf(mx[r], om);
      sm[r] = sm[r]*__expf(mx[r]-nm) + os*__expf(om-nm);
      mx[r] = nm;
    }
    if (lane==0 && rows[r] >= 0){
      stats[(size_t)rows[r]*6 + ci*2 + 0] = mx[r];
      stats[(size_t)rows[r]*6 + ci*2 + 1] = sm[r];
    }
  }
}

// ---------------- target logit for tail clusters (one wave per row) ----------------
__global__ __launch_bounds__(256) void k_tlogit(
    const int* __restrict__ tgtmap, const float* __restrict__ combo,
    const float* __restrict__ w0, const float* __restrict__ w1, const float* __restrict__ w2,
    float* __restrict__ tlogit)
{
  int lane = threadIdx.x & 63;
  int row = (blockIdx.x * 256 + threadIdx.x) >> 6;
  int tgt = tgtmap[row];
  float acc = 0.f;
  const float* pr = nullptr; const float* wr = nullptr; int Kp = 0;
  const float* crow = combo + (size_t)row*384;
  if      (tgt >= 1000){ pr = crow + 353; wr = w2 + (size_t)(tgt-1000)*16;  Kp=16;  }
  else if (tgt >= 100) { pr = crow + 289; wr = w1 + (size_t)(tgt-100)*64;   Kp=64;  }
  else if (tgt >= 30)  { pr = crow + 33;  wr = w0 + (size_t)(tgt-30)*256;   Kp=256; }
  for (int k=lane; k<Kp; k+=64) acc += pr[k]*wr[k];
  for (int off=32; off; off>>=1) acc += __shfl_down(acc, off);
  if (lane==0) tlogit[row] = acc;
}

// ---------------- final: head LSE + assemble NLL, reduce ----------------
__global__ __launch_bounds__(256) void k_final(
    const float* __restrict__ combo, const float* __restrict__ stats,
    const float* __restrict__ tlogit, const int* __restrict__ tgtmap,
    float* __restrict__ out)
{
  int row = blockIdx.x*256 + threadIdx.x;
  int tgt = tgtmap[row];
  float nll = 0.f;
  if (tgt != 0){
    const float* hrow = combo + (size_t)row*384;
    float m = hrow[0];
    #pragma unroll
    for (int i=1;i<33;i++) m = fmaxf(m, hrow[i]);
    float s = 0.f;
    #pragma unroll
    for (int i=0;i<33;i++) s += __expf(hrow[i]-m);
    float lse = __logf(s) + m;
    int ci = (tgt>=1000) ? 2 : (tgt>=100) ? 1 : (tgt>=30) ? 0 : -1;
    if (ci < 0){
      nll = lse - hrow[tgt];
    } else {
      float cm = stats[(size_t)row*6 + ci*2 + 0];
      float cs = stats[(size_t)row*6 + ci*2 + 1];
      nll = lse - hrow[30+ci] + (__logf(cs) + cm - tlogit[row]);
    }
  }
  float v = nll;
  for (int off=32; off; off>>=1) v += __shfl_down(v, off);
  __shared__ float wsum[4];
  int lane = threadIdx.x & 63, wv = threadIdx.x >> 6;
  if (lane==0) wsum[wv] = v;
  __syncthreads();
  if (threadIdx.x==0) atomicAdd(out, wsum[0]+wsum[1]+wsum[2]+wsum[3]);
}

extern "C" void kernel_launch(void* const* d_in, const int* in_sizes, int n_in,
                              void* d_out, int out_size, void* d_ws, size_t ws_size,
                              hipStream_t stream)
{
  const float* z      = (const float*)d_in[0];
  const float* emb    = (const float*)d_in[1];
  const float* l2h_w  = (const float*)d_in[2];
  const float* l2h_b  = (const float*)d_in[3];
  const float* w0ih   = (const float*)d_in[4];
  const float* w0hh   = (const float*)d_in[5];
  const float* b0ih   = (const float*)d_in[6];
  const float* b0hh   = (const float*)d_in[7];
  const float* w1ih   = (const float*)d_in[8];
  const float* w1hh   = (const float*)d_in[9];
  const float* b1ih   = (const float*)d_in[10];
  const float* b1hh   = (const float*)d_in[11];
  const float* head_w = (const float*)d_in[12];
  const float* p0     = (const float*)d_in[13];
  const float* tw0    = (const float*)d_in[14];
  const float* p1     = (const float*)d_in[15];
  const float* tw1    = (const float*)d_in[16];
  const float* p2     = (const float*)d_in[17];
  const float* tw2    = (const float*)d_in[18];
  const int* inp_seq  = (const int*)d_in[19];
  const int* tgt_seq  = (const int*)d_in[20];
  const int* length   = (const int*)d_in[21];

  float* ws   = (float*)d_ws;
  ushort* hb0 = (ushort*)ws;                      // 65536 ushorts (2 layers initial)
  ushort* hx  = hb0 + 65536;                      // 131072 ushorts: h1 ping/pong, h2 ping/pong
  float* bufA = ws + 98304;                       // 8192*1024  (pre0; later combo etc.)
  float* bufB = bufA + (size_t)NROW*HH;           // 8192*1024  (h2)
  int*   ibuf = (int*)(bufB + (size_t)NROW*HH);
  int* sorted_idx = ibuf;                         // 32
  int* tokmap = ibuf + 32;                        // 8192
  int* tgtmap = tokmap + NROW;                    // 8192
  int* flags  = tgtmap + NROW;                    // 512 ints: 8 sub-counters @128B
  int* bincnt = flags + 512;                      // 3 (+pad to 32)
  int* blist0 = bincnt + 32;                      // 8192
  int* blist1 = blist0 + NROW;                    // 8192
  int* blist2 = blist1 + NROW;                    // 8192
  float* combo = bufA;                            // 8192*384 (head 0..32 | p0 33..288 | p1 289..352 | p2 353..368)
  float* stats = bufA + (size_t)NROW*384;         // 8192*6
  float* tlog  = stats + (size_t)NROW*6;          // 8192
  float* wcat  = tlog + NROW;                     // 384*1024

  float* outF = (float*)d_out;
  hipMemsetAsync(outF, 0, sizeof(float), stream);
  hipMemsetAsync(flags, 0, 544*sizeof(int), stream);

  k_sort<<<1, 32, 0, stream>>>(length, sorted_idx);
  k_maps<<<32, 256, 0, stream>>>(sorted_idx, inp_seq, tgt_seq, tokmap, tgtmap);
  k_hid<<<256, 256, 0, stream>>>(z, l2h_w, l2h_b, hb0);
  k_bin<<<32, 256, 0, stream>>>(tgtmap, bincnt, blist0, blist1, blist2);

  // pre0 = emb[tok] @ w0ih^T + b0ih + b0hh   (bf16 MFMA, A gathered)
  k_gemm_bf16<<<dim3(HH/128, NROW/128), 256, 0, stream>>>(emb, EE, tokmap, w0ih,
                                                          b0ih, b0hh, bufA, NROW, HH, EE);
  // fused 2-layer pipelined recurrence: bufB := h2 (W1ih applied in-kernel)
  k_rnn_fused<<<NWG, 256, 0, stream>>>(bufA, bufB, w0hh, w1ih, w1hh, b1ih, b1hh,
                                       hb0, hx, flags);

  // single fused output GEMM: combo = h2 @ [head;p0;p1;p2]^T  (N=384, A read once)
  k_wcat<<<384, 256, 0, stream>>>(head_w, p0, p1, p2, wcat);
  k_gemm_bf16<<<dim3(3, NROW/128), 256, 0, stream>>>(bufB, HH, nullptr, wcat,
                                                     nullptr, nullptr, combo, NROW, 384, HH);

  // cluster LSE only for rows whose TARGET is in that cluster (binned lists)
  k_cluster<<<NROW/16, 256, 0, stream>>>(combo, 33,  384, 256, tw0, 70,
                                         blist0, bincnt, 0, stats);
  k_cluster<<<NROW/16, 256, 0, stream>>>(combo, 289, 384, 64,  tw1, 900,
                                         blist1, bincnt, 1, stats);
  k_cluster<<<NROW/16, 256, 0, stream>>>(combo, 353, 384, 16,  tw2, 19000,
                                         blist2, bincnt, 2, stats);
  k_tlogit<<<NROW/4, 256, 0, stream>>>(tgtmap, combo, tw0, tw1, tw2, tlog);
  k_final<<<NROW/256, 256, 0, stream>>>(combo, stats, tlog, tgtmap, outF);
}